// Round 12
// baseline (788.604 us; speedup 1.0000x reference)
//
#include <hip/hip_runtime.h>
#include <hip/hip_cooperative_groups.h>
#include <math.h>

namespace cg = cooperative_groups;

#define CHUNK 8192
#define BSH 8            // bucket shift: 256 nodes per bucket
#define BNODES 256
#define RAWCAP 9216      // LDS edge capacity per bucket (avg 8192, sigma ~90)
#define MAXCELL 512      // max chunks supported (E <= 4.19M); also requires nb <= 511

// Workspace layout (4-byte units, NO aliasing; ~33 MB total):
//   dinv, ptrS, base, off(ushort), csr, temp, h0u, h1u, g  -- same as round 11.

union H2 { unsigned int u; _Float16 h[2]; };

struct MegaArgs {
    const int* row; const int* col;
    int* temp; unsigned short* off; int* base; int* ptrS;
    float* dinv; int* csr;
    const float* x; const float* W1; unsigned int* h0u;
    const float* W2; const float* b1; unsigned int* h1u;
    const float* b2; const int* batch; float* g;
    const float* Wl; const float* bl; float* out;
    int E, NBLK, nb, N, G;
};

struct SmemBin { int cnt[512]; int cur[512]; int wsum[16]; int stage[CHUNK]; };
struct SmemBuild {
    int cnt[BNODES]; int cur[BNODES]; int cellstart[MAXCELL]; int soff[MAXCELL];
    int wsum[16]; float sdinv[BNODES]; int raw[RAWCAP]; int stage[RAWCAP];
};
struct SmemGat { float sW[256]; };

__global__ __launch_bounds__(1024) void k_mega(MegaArgs a) {
    cg::grid_group grid = cg::this_grid();
    __shared__ union { SmemBin b; SmemBuild u; SmemGat gt; } sm;
    const int t = threadIdx.x;                 // 1024 threads = 16 waves
    const int wid = t >> 6, lane = t & 63;
    const int NBLK = a.NBLK, nb = a.nb, N = a.N, E = a.E;

    // ---- Phase 1: BIN (grid-stride over chunks) ----
    for (int blk = blockIdx.x; blk < NBLK; blk += gridDim.x) {
        int start = blk * CHUNK;
        int cs = E - start; if (cs > CHUNK) cs = CHUNK;
        if (t < 512) sm.b.cnt[t] = 0;
        __syncthreads();
        for (int i = t; i < cs; i += 1024) atomicAdd(&sm.b.cnt[a.col[start + i] >> BSH], 1);
        __syncthreads();
        if (t < 512) {
            int c = sm.b.cnt[t];
            int incl = c;
            for (int o = 1; o < 64; o <<= 1) { int u = __shfl_up(incl, o, 64); if (lane >= o) incl += u; }
            if (lane == 63) sm.b.wsum[wid] = incl;
            sm.b.cnt[t] = incl - c;
        }
        __syncthreads();
        if (t < 512) {
            int wb = 0;
            for (int i = 0; i < wid; ++i) wb += sm.b.wsum[i];
            int excl = sm.b.cnt[t] + wb;
            if (t < nb) a.off[t * NBLK + blk] = (unsigned short)excl;
            if (t == 0) a.off[nb * NBLK + blk] = (unsigned short)cs;
            sm.b.cur[t] = excl;
        }
        __syncthreads();
        for (int i = t; i < cs; i += 1024) {
            int cc = a.col[start + i];
            int rr = a.row[start + i];
            int p = atomicAdd(&sm.b.cur[cc >> BSH], 1);
            sm.b.stage[p] = (rr << BSH) | (cc & (BNODES - 1));
        }
        __syncthreads();
        for (int i = t; i < cs; i += 1024) a.temp[start + i] = sm.b.stage[i];
        __syncthreads();
    }
    __threadfence();
    grid.sync();

    // ---- Phase 2: BASE (off-table row sums, one wave per row) + zero g ----
    {
        int nbp1 = nb + 1;
        int wstride = gridDim.x * 16;
        for (int rowi = blockIdx.x * 16 + wid; rowi < nbp1; rowi += wstride) {
            const unsigned short* orow = a.off + (size_t)rowi * NBLK;
            int s = 0;
            for (int ch = lane; ch < NBLK; ch += 64) s += orow[ch];
            for (int o = 32; o > 0; o >>= 1) s += __shfl_down(s, o, 64);
            if (lane == 0) {
                a.base[rowi] = s;
                if (rowi == nb) a.ptrS[N] = s;   // = E
            }
        }
        int G16 = a.G * 16;
        for (int i = blockIdx.x * 1024 + t; i < G16; i += gridDim.x * 1024) a.g[i] = 0.0f;
    }
    __threadfence();
    grid.sync();

    // ---- Phase 3: BUILD + fused xw1 (grid-stride over buckets) ----
    for (int b = blockIdx.x; b < nb; b += gridDim.x) {
        if (t < BNODES) sm.u.cnt[t] = 0;
        int len0 = 0;
        if (t < MAXCELL) {
            int s0v = 0;
            if (t < NBLK) {
                s0v = (int)a.off[b * NBLK + t];
                len0 = (int)a.off[(b + 1) * NBLK + t] - s0v;
            }
            sm.u.soff[t] = s0v;
            int v = len0;
            for (int o = 1; o < 64; o <<= 1) { int u = __shfl_up(v, o, 64); if (lane >= o) v += u; }
            if (lane == 63) sm.u.wsum[wid] = v;
            sm.u.cellstart[t] = v - len0;
        }
        __syncthreads();
        if (t < MAXCELL) {
            int wb = 0;
            for (int i = 0; i < wid; ++i) wb += sm.u.wsum[i];
            sm.u.cellstart[t] += wb;
        }
        __syncthreads();
        int bb = a.base[b];
        int total = a.base[b + 1] - bb;
        int grp = t >> 4, gl = t & 15;
        for (int cell = grp; cell < NBLK; cell += 64) {
            int s0 = sm.u.soff[cell];
            int rb = sm.u.cellstart[cell];
            int len = ((cell + 1 < NBLK) ? sm.u.cellstart[cell + 1] : total) - rb;
            const int* src = a.temp + cell * CHUNK + s0;
            for (int j = gl; j < len; j += 16) {
                int e = src[j];
                atomicAdd(&sm.u.cnt[e & (BNODES - 1)], 1);
                int idx = rb + j;
                if (idx < RAWCAP) sm.u.raw[idx] = e;
            }
        }
        __syncthreads();
        int c = 0, sincl = 0;
        if (t < BNODES) {
            c = sm.u.cnt[t];
            sincl = c;
            for (int o = 1; o < 64; o <<= 1) { int u = __shfl_up(sincl, o, 64); if (lane >= o) sincl += u; }
            if (lane == 63) sm.u.wsum[wid] = sincl;
        }
        __syncthreads();
        if (t < BNODES) {
            int wb2 = 0;
            for (int i = 0; i < wid; ++i) wb2 += sm.u.wsum[i];
            int lstart = sincl - c + wb2;
            int node = (b << BSH) + t;
            float dv = rsqrtf(1.0f + (float)c);
            sm.u.sdinv[t] = dv;
            if (node < N) { a.ptrS[node] = bb + lstart; a.dinv[node] = dv; }
            sm.u.cur[t] = lstart;
        }
        __syncthreads();
        int cap = total > RAWCAP ? RAWCAP : total;
        for (int i = t; i < cap; i += 1024) {
            int e = sm.u.raw[i];
            int p = atomicAdd(&sm.u.cur[e & (BNODES - 1)], 1);
            int r = e >> BSH;
            if (p < RAWCAP) sm.u.stage[p] = r;
            else            a.csr[bb + p] = r;   // statistically unreachable
        }
        if (total > RAWCAP) {                    // statistically unreachable spill
            for (int cell = grp; cell < NBLK; cell += 64) {
                int s0 = sm.u.soff[cell];
                int rb = sm.u.cellstart[cell];
                int len = ((cell + 1 < NBLK) ? sm.u.cellstart[cell + 1] : total) - rb;
                const int* src = a.temp + cell * CHUNK + s0;
                for (int j = gl; j < len; j += 16) {
                    if (rb + j >= RAWCAP) {
                        int e = src[j];
                        int p = atomicAdd(&sm.u.cur[e & (BNODES - 1)], 1);
                        int r = e >> BSH;
                        if (p < RAWCAP) sm.u.stage[p] = r;
                        else            a.csr[bb + p] = r;
                    }
                }
            }
        }
        __syncthreads();
        for (int i = t; i < cap; i += 1024) a.csr[bb + i] = sm.u.stage[i];
        // fused xw1 epilogue for this bucket's nodes
        for (int i = t; i < BNODES * 8; i += 1024) {
            int vl = i >> 3, k2 = i & 7, k = k2 * 2;
            int v = (b << BSH) + vl;
            if (v < N) {
                float x0 = a.x[v * 3 + 0], x1 = a.x[v * 3 + 1], x2 = a.x[v * 3 + 2];
                float d = sm.u.sdinv[vl];
                H2 p;
                p.h[0] = (_Float16)(d * (x0 * a.W1[k]     + x1 * a.W1[16 + k]     + x2 * a.W1[32 + k]));
                p.h[1] = (_Float16)(d * (x0 * a.W1[k + 1] + x1 * a.W1[16 + k + 1] + x2 * a.W1[32 + k + 1]));
                a.h0u[v * 8 + k2] = p.u;
            }
        }
        __syncthreads();
    }
    __threadfence();
    grid.sync();

    // ---- Phase 4: GATHER1 (8 lanes/node, packed u32; relu + W2 via shfl) ----
    if (t < 256) sm.gt.sW[t] = a.W2[t];
    __syncthreads();
    {
        int n8 = N * 8;
        int stride = gridDim.x * 1024;
        for (int t0 = blockIdx.x * 1024 + t; t0 < n8; t0 += stride) {
            int v = t0 >> 3, gl = t0 & 7, k = gl * 2;
            int s = a.ptrS[v], e = a.ptrS[v + 1];
            float al0 = 0.0f, ah0 = 0.0f, al1 = 0.0f, ah1 = 0.0f;
            int i = s;
            for (; i + 7 < e; i += 8) {
                int myr = __builtin_nontemporal_load(a.csr + i + gl);
#pragma unroll
                for (int q = 0; q < 8; ++q) {
                    int r = __shfl(myr, q, 8);
                    H2 p; p.u = a.h0u[r * 8 + gl];
                    if (q & 1) { al1 += (float)p.h[0]; ah1 += (float)p.h[1]; }
                    else       { al0 += (float)p.h[0]; ah0 += (float)p.h[1]; }
                }
            }
            if (i < e) {
                int rem = e - i;
                int myr = (gl < rem) ? __builtin_nontemporal_load(a.csr + i + gl) : 0;
                for (int q = 0; q < rem; ++q) {
                    int r = __shfl(myr, q, 8);
                    H2 p; p.u = a.h0u[r * 8 + gl];
                    al0 += (float)p.h[0]; ah0 += (float)p.h[1];
                }
            }
            H2 selfp; selfp.u = a.h0u[v * 8 + gl];
            float d = a.dinv[v];
            float h_lo = fmaxf(d * (al0 + al1 + (float)selfp.h[0]) + a.b1[k], 0.0f);
            float h_hi = fmaxf(d * (ah0 + ah1 + (float)selfp.h[1]) + a.b1[k + 1], 0.0f);
            float o0 = 0.0f, o1 = 0.0f;
#pragma unroll
            for (int j = 0; j < 8; ++j) {
                float hl = __shfl(h_lo, j, 8);
                float hh = __shfl(h_hi, j, 8);
                o0 += hl * sm.gt.sW[(2 * j) * 16 + k]     + hh * sm.gt.sW[(2 * j + 1) * 16 + k];
                o1 += hl * sm.gt.sW[(2 * j) * 16 + k + 1] + hh * sm.gt.sW[(2 * j + 1) * 16 + k + 1];
            }
            H2 outp;
            outp.h[0] = (_Float16)(d * o0);
            outp.h[1] = (_Float16)(d * o1);
            __builtin_nontemporal_store(outp.u, a.h1u + v * 8 + gl);
        }
    }
    __threadfence();
    grid.sync();

    // ---- Phase 5: GATHER2 + pool (uniform iteration count for wave reduction) ----
    {
        int n8 = N * 8;
        int stride = gridDim.x * 1024;
        int iters = (n8 + stride - 1) / stride;
        for (int it = 0; it < iters; ++it) {
            int t0 = it * stride + blockIdx.x * 1024 + t;
            int v = t0 >> 3, gl = t0 & 7, k = gl * 2;
            bool valid = (t0 < n8);
            float val0 = 0.0f, val1 = 0.0f;
            int bg = 0;
            if (valid) {
                int s = a.ptrS[v], e = a.ptrS[v + 1];
                float al0 = 0.0f, ah0 = 0.0f, al1 = 0.0f, ah1 = 0.0f;
                int i = s;
                for (; i + 7 < e; i += 8) {
                    int myr = __builtin_nontemporal_load(a.csr + i + gl);
#pragma unroll
                    for (int q = 0; q < 8; ++q) {
                        int r = __shfl(myr, q, 8);
                        H2 p; p.u = a.h1u[r * 8 + gl];
                        if (q & 1) { al1 += (float)p.h[0]; ah1 += (float)p.h[1]; }
                        else       { al0 += (float)p.h[0]; ah0 += (float)p.h[1]; }
                    }
                }
                if (i < e) {
                    int rem = e - i;
                    int myr = (gl < rem) ? __builtin_nontemporal_load(a.csr + i + gl) : 0;
                    for (int q = 0; q < rem; ++q) {
                        int r = __shfl(myr, q, 8);
                        H2 p; p.u = a.h1u[r * 8 + gl];
                        al0 += (float)p.h[0]; ah0 += (float)p.h[1];
                    }
                }
                H2 selfp; selfp.u = a.h1u[v * 8 + gl];
                float d = a.dinv[v];
                val0 = d * (al0 + al1 + (float)selfp.h[0]) + a.b2[k];
                val1 = d * (ah0 + ah1 + (float)selfp.h[1]) + a.b2[k + 1];
                bg = a.batch[v];
            }
            int bg0 = __shfl(bg, lane & 7, 64);
            bool uni = __all(valid && (bg == bg0));
            if (uni) {
                val0 += __shfl_xor(val0, 8, 64);
                val0 += __shfl_xor(val0, 16, 64);
                val0 += __shfl_xor(val0, 32, 64);
                val1 += __shfl_xor(val1, 8, 64);
                val1 += __shfl_xor(val1, 16, 64);
                val1 += __shfl_xor(val1, 32, 64);
                if (lane < 8) {
                    atomicAdd(&a.g[bg * 16 + k], val0);
                    atomicAdd(&a.g[bg * 16 + k + 1], val1);
                }
            } else if (valid) {
                atomicAdd(&a.g[bg * 16 + k], val0);
                atomicAdd(&a.g[bg * 16 + k + 1], val1);
            }
        }
    }
    __threadfence();
    grid.sync();

    // ---- Phase 6: HEAD ----
    for (int gi = blockIdx.x * 1024 + t; gi < a.G; gi += gridDim.x * 1024) {
        float gv[16];
#pragma unroll
        for (int k = 0; k < 16; ++k) gv[k] = a.g[gi * 16 + k];
        float lo[7];
        float mx = -1e30f;
#pragma unroll
        for (int j = 0; j < 7; ++j) {
            float acc = a.bl[j];
#pragma unroll
            for (int k = 0; k < 16; ++k) acc += gv[k] * a.Wl[k * 7 + j];
            lo[j] = acc;
            mx = fmaxf(mx, acc);
        }
        float ssum = 0.0f;
#pragma unroll
        for (int j = 0; j < 7; ++j) ssum += expf(lo[j] - mx);
        float lse = mx + logf(ssum);
#pragma unroll
        for (int j = 0; j < 7; ++j) a.out[gi * 7 + j] = lo[j] - lse;
    }
}

extern "C" void kernel_launch(void* const* d_in, const int* in_sizes, int n_in,
                              void* d_out, int out_size, void* d_ws, size_t ws_size,
                              hipStream_t stream) {
    const float* x    = (const float*)d_in[0];
    const int*   ei   = (const int*)d_in[1];   // [2, E]: row = ei[0:E), col = ei[E:2E)
    const int*   batch = (const int*)d_in[3];
    const float* W1 = (const float*)d_in[4];
    const float* b1 = (const float*)d_in[5];
    const float* W2 = (const float*)d_in[6];
    const float* b2 = (const float*)d_in[7];
    const float* Wl = (const float*)d_in[8];
    const float* bl = (const float*)d_in[9];
    float* out = (float*)d_out;

    const int N = in_sizes[0] / 3;
    const int E = in_sizes[1] / 2;
    const int G = out_size / 7;

    const int* row = ei;
    const int* col = ei + E;

    const int NBLK = (E + CHUNK - 1) / CHUNK;   // must be <= MAXCELL
    const int nb   = (N + BNODES - 1) >> BSH;   // must be <= 511

    int* w = (int*)d_ws;
    float* dinv = (float*)w;            w += N;
    int*   ptrS = w;                    w += N + 1;
    int*   base = w;                    w += nb + 1;
    unsigned short* off = (unsigned short*)w;
    w += ((nb + 1) * NBLK + 1) / 2;     // ushort table, rounded up to int units
    int*   csr  = w;                    w += E;
    int*   temp = w;                    w += E;
    unsigned int* h0u = (unsigned int*)w;  w += 8 * N;
    unsigned int* h1u = (unsigned int*)w;  w += 8 * N;
    float* g    = (float*)w;            w += 16 * G;

    // Cooperative grid sizing (cached; query-only, graph-capture-safe).
    static int gridBlocks = 0;
    if (gridBlocks == 0) {
        int numBlocks = 0;
        hipOccupancyMaxActiveBlocksPerMultiprocessor(&numBlocks, k_mega, 1024, 0);
        if (numBlocks < 1) numBlocks = 1;
        hipDeviceProp_t prop;
        int dev = 0;
        hipGetDevice(&dev);
        hipGetDeviceProperties(&prop, dev);
        gridBlocks = numBlocks * prop.multiProcessorCount;
    }

    MegaArgs a;
    a.row = row; a.col = col; a.temp = temp; a.off = off; a.base = base; a.ptrS = ptrS;
    a.dinv = dinv; a.csr = csr; a.x = x; a.W1 = W1; a.h0u = h0u;
    a.W2 = W2; a.b1 = b1; a.h1u = h1u; a.b2 = b2; a.batch = batch; a.g = g;
    a.Wl = Wl; a.bl = bl; a.out = out;
    a.E = E; a.NBLK = NBLK; a.nb = nb; a.N = N; a.G = G;

    void* kargs[] = { (void*)&a };
    hipLaunchCooperativeKernel((const void*)k_mega, dim3(gridBlocks), dim3(1024),
                               kargs, 0, stream);
}

// Round 13
// 463.932 us; speedup vs baseline: 1.6998x; 1.6998x over previous
//
#include <hip/hip_runtime.h>
#include <math.h>

#define CHUNK 8192
#define BSH 8            // bucket shift: 256 nodes per bucket
#define BNODES 256
#define RAWCAP 9216      // LDS edge capacity per bucket (avg 8192, sigma ~90)
#define MAXCELL 512      // max chunks supported (E <= 4.19M); also requires nb <= 511

// Workspace layout (4-byte units, NO aliasing; ~33 MB total):
//   dinv  : N            rsqrt(1+deg)
//   ptrS  : N+1          CSR row starts (ptrS[N] = E)
//   off   : (nb+1)*NBLK  ushort per-(bucket,chunk) exclusive offsets
//   csr   : E            source nodes grouped by destination
//   temp  : E            binned packed edges
//   h0u   : 8N u32       packed fp16 feature table, layer-1 input (dinv-premultiplied)
//   h1u   : 8N u32       packed fp16 feature table, layer-2 input
//   g     : 16G          pooled graph accumulator
//   cnt1  : 1            gather2 completion ticket counter

union H2 { unsigned int u; _Float16 h[2]; };

// Phase 1: bin this block's 8192-edge chunk by destination bucket.
// Also zeroes g and the ticket counter (grid-stride / block 0).
__global__ __launch_bounds__(1024) void k_bin(
                      const int* __restrict__ row, const int* __restrict__ col,
                      int* __restrict__ temp, unsigned short* __restrict__ off,
                      float* __restrict__ g, int* __restrict__ cnt1,
                      int E, int NBLK, int nb, int G16) {
    __shared__ int cnt[512];
    __shared__ int cur[512];
    __shared__ int wsum[16];
    __shared__ int stage[CHUNK];
    int blk = blockIdx.x;
    int start = blk * CHUNK;
    int cs = E - start; if (cs > CHUNK) cs = CHUNK;
    int t = threadIdx.x;     // 1024 threads = 16 waves
    int wid = t >> 6, lane = t & 63;
    for (int i = blk * 1024 + t; i < G16; i += gridDim.x * 1024) g[i] = 0.0f;
    if (blk == 0 && t == 0) atomicExch(cnt1, 0);
    if (t < 512) cnt[t] = 0;
    __syncthreads();
    for (int i = t; i < cs; i += 1024) atomicAdd(&cnt[col[start + i] >> BSH], 1);
    __syncthreads();
    if (t < 512) {           // waves 0..7 scan the 512 bucket counters
        int c = cnt[t];
        int incl = c;
        for (int o = 1; o < 64; o <<= 1) {
            int u = __shfl_up(incl, o, 64);
            if (lane >= o) incl += u;
        }
        if (lane == 63) wsum[wid] = incl;
        cnt[t] = incl - c;   // within-wave exclusive
    }
    __syncthreads();
    if (t < 512) {
        int wb = 0;
        for (int i = 0; i < wid; ++i) wb += wsum[i];
        int excl = cnt[t] + wb;
        if (t < nb) off[t * NBLK + blk] = (unsigned short)excl;
        if (t == 0) off[nb * NBLK + blk] = (unsigned short)cs;
        cur[t] = excl;
    }
    __syncthreads();
    for (int i = t; i < cs; i += 1024) {
        int cc = col[start + i];         // L2-hot re-read (same 32KB window)
        int rr = row[start + i];
        int p = atomicAdd(&cur[cc >> BSH], 1);
        stage[p] = (rr << BSH) | (cc & (BNODES - 1));
    }
    __syncthreads();
    for (int i = t; i < cs; i += 1024) temp[start + i] = stage[i];
}

// Phase 2: one block per 256-node bucket, 1024 threads. Computes its own
// bucket base bb = sum of off row b (no base[] array, no k_base kernel),
// builds ptrS/dinv/csr (LDS-staged, coalesced writeback), and fused xw1.
__global__ __launch_bounds__(1024) void k_build(
                        const int* __restrict__ temp, const unsigned short* __restrict__ off,
                        int* __restrict__ ptrS, float* __restrict__ dinv,
                        int* __restrict__ csr,
                        const float* __restrict__ x, const float* __restrict__ W1,
                        unsigned int* __restrict__ h0u, int NBLK, int N, int nb) {
    __shared__ int cnt[BNODES];
    __shared__ int cur[BNODES];
    __shared__ int cellstart[MAXCELL];
    __shared__ int soff[MAXCELL];
    __shared__ int wsum[16];
    __shared__ float sdinv[BNODES];
    __shared__ int s_bb, s_total;
    __shared__ int raw[RAWCAP];
    __shared__ int stage[RAWCAP];
    int b = blockIdx.x;
    int t = threadIdx.x;     // 1024 threads = 16 waves
    int wid = t >> 6, lane = t & 63;
    if (t < BNODES) cnt[t] = 0;
    // phase 0: cell lengths + exclusive scan; also capture s0v for bb reduction
    int len0 = 0, s0v = 0;
    if (t < MAXCELL) {
        if (t < NBLK) {
            s0v = (int)off[b * NBLK + t];
            len0 = (int)off[(b + 1) * NBLK + t] - s0v;
        }
        soff[t] = s0v;
        int v = len0;
        for (int o = 1; o < 64; o <<= 1) {
            int u = __shfl_up(v, o, 64);
            if (lane >= o) v += u;
        }
        if (lane == 63) wsum[wid] = v;
        cellstart[t] = v - len0;
    }
    __syncthreads();
    if (t < MAXCELL) {
        int wb = 0;
        for (int i = 0; i < wid; ++i) wb += wsum[i];
        cellstart[t] += wb;
    }
    if (t == NBLK - 1) s_total = cellstart[t] + len0;   // own value, just updated
    __syncthreads();                                    // wsum now reusable
    // bb = sum of off row b (s0v across t<NBLK; 0 elsewhere)
    int sv = s0v;
    for (int o = 32; o > 0; o >>= 1) sv += __shfl_down(sv, o, 64);
    if (lane == 0 && wid < 8) wsum[wid] = sv;
    __syncthreads();
    if (t == 0) {
        int bbl = 0;
        for (int i = 0; i < 8; ++i) bbl += wsum[i];
        s_bb = bbl;
    }
    __syncthreads();
    int bb = s_bb;
    int total = s_total;
    if (b == nb - 1 && t == 0) ptrS[N] = bb + total;    // = E
    // Phase A: 16-lane-group per cell, coalesced load into raw[], histogram fused
    int grp = t >> 4, gl = t & 15;     // 64 groups of 16 lanes
    for (int cell = grp; cell < NBLK; cell += 64) {
        int s0 = soff[cell];
        int rb = cellstart[cell];
        int len = ((cell + 1 < NBLK) ? cellstart[cell + 1] : total) - rb;
        const int* src = temp + cell * CHUNK + s0;
        for (int j = gl; j < len; j += 16) {
            int e = src[j];
            atomicAdd(&cnt[e & (BNODES - 1)], 1);
            int idx = rb + j;
            if (idx < RAWCAP) raw[idx] = e;
        }
    }
    __syncthreads();
    int c = 0, sincl = 0;
    if (t < BNODES) {
        c = cnt[t];
        sincl = c;
        for (int o = 1; o < 64; o <<= 1) {
            int u = __shfl_up(sincl, o, 64);
            if (lane >= o) sincl += u;
        }
        if (lane == 63) wsum[wid] = sincl;
    }
    __syncthreads();
    if (t < BNODES) {
        int wb2 = 0;
        for (int i = 0; i < wid; ++i) wb2 += wsum[i];
        int lstart = sincl - c + wb2;
        int node = (b << BSH) + t;
        float dv = rsqrtf(1.0f + (float)c);
        sdinv[t] = dv;
        if (node < N) {
            ptrS[node] = bb + lstart;
            dinv[node] = dv;
        }
        cur[t] = lstart;
    }
    __syncthreads();
    int cap = total > RAWCAP ? RAWCAP : total;
    for (int i = t; i < cap; i += 1024) {
        int e = raw[i];
        int p = atomicAdd(&cur[e & (BNODES - 1)], 1);
        int r = e >> BSH;
        if (p < RAWCAP) stage[p] = r;
        else            csr[bb + p] = r;   // statistically unreachable
    }
    if (total > RAWCAP) {                  // statistically unreachable spill
        for (int cell = grp; cell < NBLK; cell += 64) {
            int s0 = soff[cell];
            int rb = cellstart[cell];
            int len = ((cell + 1 < NBLK) ? cellstart[cell + 1] : total) - rb;
            const int* src = temp + cell * CHUNK + s0;
            for (int j = gl; j < len; j += 16) {
                if (rb + j >= RAWCAP) {
                    int e = src[j];
                    int p = atomicAdd(&cur[e & (BNODES - 1)], 1);
                    int r = e >> BSH;
                    if (p < RAWCAP) stage[p] = r;
                    else            csr[bb + p] = r;
                }
            }
        }
    }
    __syncthreads();
    for (int i = t; i < cap; i += 1024) csr[bb + i] = stage[i];
    // Fused xw1 epilogue for this bucket's 256 nodes (2048 packed u32 writes).
    for (int i = t; i < BNODES * 8; i += 1024) {
        int vl = i >> 3, k2 = i & 7, k = k2 * 2;
        int v = (b << BSH) + vl;
        if (v < N) {
            float x0 = x[v * 3 + 0], x1 = x[v * 3 + 1], x2 = x[v * 3 + 2];
            float d = sdinv[vl];
            H2 p;
            p.h[0] = (_Float16)(d * (x0 * W1[k]     + x1 * W1[16 + k]     + x2 * W1[32 + k]));
            p.h[1] = (_Float16)(d * (x0 * W1[k + 1] + x1 * W1[16 + k + 1] + x2 * W1[32 + k + 1]));
            h0u[v * 8 + k2] = p.u;
        }
    }
}

// Layer-1 gather: 8 lanes/node, packed-u32 rows (unchanged from round 11).
__global__ void k_gather1(const int* __restrict__ ptrS, const int* __restrict__ csr,
                          const float* __restrict__ dinv, const unsigned int* __restrict__ h0u,
                          const float* __restrict__ W2, const float* __restrict__ b1,
                          unsigned int* __restrict__ h1u, int N) {
    __shared__ float sW[256];
    sW[threadIdx.x] = W2[threadIdx.x];
    __syncthreads();
    int t = blockIdx.x * blockDim.x + threadIdx.x;
    int v = t >> 3, gl = t & 7, k = gl * 2;
    if (v >= N) return;
    int s = ptrS[v], e = ptrS[v + 1];
    float al0 = 0.0f, ah0 = 0.0f, al1 = 0.0f, ah1 = 0.0f;
    int i = s;
    for (; i + 7 < e; i += 8) {
        int myr = __builtin_nontemporal_load(csr + i + gl);
#pragma unroll
        for (int q = 0; q < 8; ++q) {
            int r = __shfl(myr, q, 8);
            H2 p; p.u = h0u[r * 8 + gl];
            if (q & 1) { al1 += (float)p.h[0]; ah1 += (float)p.h[1]; }
            else       { al0 += (float)p.h[0]; ah0 += (float)p.h[1]; }
        }
    }
    if (i < e) {
        int rem = e - i;
        int myr = (gl < rem) ? __builtin_nontemporal_load(csr + i + gl) : 0;
        for (int q = 0; q < rem; ++q) {
            int r = __shfl(myr, q, 8);
            H2 p; p.u = h0u[r * 8 + gl];
            al0 += (float)p.h[0]; ah0 += (float)p.h[1];
        }
    }
    H2 selfp; selfp.u = h0u[v * 8 + gl];
    float d = dinv[v];
    float h_lo = fmaxf(d * (al0 + al1 + (float)selfp.h[0]) + b1[k], 0.0f);
    float h_hi = fmaxf(d * (ah0 + ah1 + (float)selfp.h[1]) + b1[k + 1], 0.0f);
    float o0 = 0.0f, o1 = 0.0f;
#pragma unroll
    for (int j = 0; j < 8; ++j) {
        float hl = __shfl(h_lo, j, 8);
        float hh = __shfl(h_hi, j, 8);
        o0 += hl * sW[(2 * j) * 16 + k]     + hh * sW[(2 * j + 1) * 16 + k];
        o1 += hl * sW[(2 * j) * 16 + k + 1] + hh * sW[(2 * j + 1) * 16 + k + 1];
    }
    H2 outp;
    outp.h[0] = (_Float16)(d * o0);
    outp.h[1] = (_Float16)(d * o1);
    __builtin_nontemporal_store(outp.u, h1u + v * 8 + gl);
}

// Layer-2 gather + pool + FUSED HEAD (last-block pattern, coherent atomic reads).
__global__ void k_gather2(const int* __restrict__ ptrS, const int* __restrict__ csr,
                          const float* __restrict__ dinv, const unsigned int* __restrict__ h1u,
                          const float* __restrict__ b2, const int* __restrict__ batch,
                          float* __restrict__ g, const float* __restrict__ Wl,
                          const float* __restrict__ bl, float* __restrict__ out,
                          int* __restrict__ cnt1, int N, int G) {
    __shared__ int s_ticket;
    int t = blockIdx.x * blockDim.x + threadIdx.x;
    int v = t >> 3, gl = t & 7, k = gl * 2;
    bool valid = (v < N);
    float val0 = 0.0f, val1 = 0.0f;
    int bg = 0;
    if (valid) {
        int s = ptrS[v], e = ptrS[v + 1];
        float al0 = 0.0f, ah0 = 0.0f, al1 = 0.0f, ah1 = 0.0f;
        int i = s;
        for (; i + 7 < e; i += 8) {
            int myr = __builtin_nontemporal_load(csr + i + gl);
#pragma unroll
            for (int q = 0; q < 8; ++q) {
                int r = __shfl(myr, q, 8);
                H2 p; p.u = h1u[r * 8 + gl];
                if (q & 1) { al1 += (float)p.h[0]; ah1 += (float)p.h[1]; }
                else       { al0 += (float)p.h[0]; ah0 += (float)p.h[1]; }
            }
        }
        if (i < e) {
            int rem = e - i;
            int myr = (gl < rem) ? __builtin_nontemporal_load(csr + i + gl) : 0;
            for (int q = 0; q < rem; ++q) {
                int r = __shfl(myr, q, 8);
                H2 p; p.u = h1u[r * 8 + gl];
                al0 += (float)p.h[0]; ah0 += (float)p.h[1];
            }
        }
        H2 selfp; selfp.u = h1u[v * 8 + gl];
        float d = dinv[v];
        val0 = d * (al0 + al1 + (float)selfp.h[0]) + b2[k];
        val1 = d * (ah0 + ah1 + (float)selfp.h[1]) + b2[k + 1];
        bg = batch[v];
    }
    int lane = threadIdx.x & 63;
    int bg0 = __shfl(bg, lane & 7, 64);
    bool uni = __all(valid && (bg == bg0));
    if (uni) {
        val0 += __shfl_xor(val0, 8, 64);
        val0 += __shfl_xor(val0, 16, 64);
        val0 += __shfl_xor(val0, 32, 64);
        val1 += __shfl_xor(val1, 8, 64);
        val1 += __shfl_xor(val1, 16, 64);
        val1 += __shfl_xor(val1, 32, 64);
        if (lane < 8) {
            atomicAdd(&g[bg * 16 + k], val0);
            atomicAdd(&g[bg * 16 + k + 1], val1);
        }
    } else if (valid) {
        atomicAdd(&g[bg * 16 + k], val0);
        atomicAdd(&g[bg * 16 + k + 1], val1);
    }
    // ---- last-block head ----
    __threadfence();
    __syncthreads();
    if (threadIdx.x == 0) s_ticket = atomicAdd(cnt1, 1);
    __syncthreads();
    if (s_ticket == (int)gridDim.x - 1) {
        __threadfence();
        for (int gi = threadIdx.x; gi < G; gi += blockDim.x) {
            float gv[16];
#pragma unroll
            for (int kk = 0; kk < 16; ++kk) gv[kk] = atomicAdd(&g[gi * 16 + kk], 0.0f);
            float lo[7];
            float mx = -1e30f;
#pragma unroll
            for (int j = 0; j < 7; ++j) {
                float a = bl[j];
#pragma unroll
                for (int kk = 0; kk < 16; ++kk) a += gv[kk] * Wl[kk * 7 + j];
                lo[j] = a;
                mx = fmaxf(mx, a);
            }
            float ssum = 0.0f;
#pragma unroll
            for (int j = 0; j < 7; ++j) ssum += expf(lo[j] - mx);
            float lse = mx + logf(ssum);
#pragma unroll
            for (int j = 0; j < 7; ++j) out[gi * 7 + j] = lo[j] - lse;
        }
    }
}

extern "C" void kernel_launch(void* const* d_in, const int* in_sizes, int n_in,
                              void* d_out, int out_size, void* d_ws, size_t ws_size,
                              hipStream_t stream) {
    const float* x    = (const float*)d_in[0];
    const int*   ei   = (const int*)d_in[1];   // [2, E]: row = ei[0:E), col = ei[E:2E)
    const int*   batch = (const int*)d_in[3];
    const float* W1 = (const float*)d_in[4];
    const float* b1 = (const float*)d_in[5];
    const float* W2 = (const float*)d_in[6];
    const float* b2 = (const float*)d_in[7];
    const float* Wl = (const float*)d_in[8];
    const float* bl = (const float*)d_in[9];
    float* out = (float*)d_out;

    const int N = in_sizes[0] / 3;
    const int E = in_sizes[1] / 2;
    const int G = out_size / 7;

    const int* row = ei;
    const int* col = ei + E;

    const int NBLK = (E + CHUNK - 1) / CHUNK;   // must be <= MAXCELL
    const int nb   = (N + BNODES - 1) >> BSH;   // must be <= 511

    int* w = (int*)d_ws;
    float* dinv = (float*)w;            w += N;
    int*   ptrS = w;                    w += N + 1;
    unsigned short* off = (unsigned short*)w;
    w += ((nb + 1) * NBLK + 1) / 2;     // ushort table, rounded up to int units
    int*   csr  = w;                    w += E;
    int*   temp = w;                    w += E;
    unsigned int* h0u = (unsigned int*)w;  w += 8 * N;
    unsigned int* h1u = (unsigned int*)w;  w += 8 * N;
    float* g    = (float*)w;            w += 16 * G;
    int*   cnt1 = w;                    w += 1;

    const int TB = 256;
    const int n8  = N * 8;
    const int G16 = G * 16;

    k_bin<<<NBLK, 1024, 0, stream>>>(row, col, temp, off, g, cnt1, E, NBLK, nb, G16);
    k_build<<<nb, 1024, 0, stream>>>(temp, off, ptrS, dinv, csr, x, W1, h0u, NBLK, N, nb);
    k_gather1<<<(n8 + TB - 1) / TB, TB, 0, stream>>>(ptrS, csr, dinv, h0u, W2, b1, h1u, N);
    k_gather2<<<(n8 + TB - 1) / TB, TB, 0, stream>>>(ptrS, csr, dinv, h1u, b2, batch,
                                                     g, Wl, bl, out, cnt1, N, G);
}

// Round 14
// 189.048 us; speedup vs baseline: 4.1714x; 2.4540x over previous
//
#include <hip/hip_runtime.h>
#include <math.h>

#define CHUNK 8192
#define BSH 8            // bucket shift: 256 nodes per bucket
#define BNODES 256
#define RAWCAP 9216      // LDS edge capacity per bucket (avg 8192, sigma ~90)
#define MAXCELL 512      // max chunks supported (E <= 4.19M); also requires nb <= 511

// Workspace layout (4-byte units, NO aliasing; ~33 MB total):
//   dinv  : N            rsqrt(1+deg)
//   ptrS  : N+1          CSR row starts (ptrS[N] = E)
//   off   : (nb+1)*NBLK  ushort per-(bucket,chunk) exclusive offsets
//   csr   : E            source nodes grouped by destination
//   temp  : E            binned packed edges
//   h0u   : 8N u32       packed fp16 feature table, layer-1 input (dinv-premultiplied)
//   h1u   : 8N u32       packed fp16 feature table, layer-2 input
//   g     : 16G          pooled graph accumulator

union H2 { unsigned int u; _Float16 h[2]; };

// Phase 1: bin this block's 8192-edge chunk by destination bucket.
// Also zeroes g (grid-stride).
__global__ __launch_bounds__(1024) void k_bin(
                      const int* __restrict__ row, const int* __restrict__ col,
                      int* __restrict__ temp, unsigned short* __restrict__ off,
                      float* __restrict__ g,
                      int E, int NBLK, int nb, int G16) {
    __shared__ int cnt[512];
    __shared__ int cur[512];
    __shared__ int wsum[16];
    __shared__ int stage[CHUNK];
    int blk = blockIdx.x;
    int start = blk * CHUNK;
    int cs = E - start; if (cs > CHUNK) cs = CHUNK;
    int t = threadIdx.x;     // 1024 threads = 16 waves
    int wid = t >> 6, lane = t & 63;
    for (int i = blk * 1024 + t; i < G16; i += gridDim.x * 1024) g[i] = 0.0f;
    if (t < 512) cnt[t] = 0;
    __syncthreads();
    for (int i = t; i < cs; i += 1024) atomicAdd(&cnt[col[start + i] >> BSH], 1);
    __syncthreads();
    if (t < 512) {           // waves 0..7 scan the 512 bucket counters
        int c = cnt[t];
        int incl = c;
        for (int o = 1; o < 64; o <<= 1) {
            int u = __shfl_up(incl, o, 64);
            if (lane >= o) incl += u;
        }
        if (lane == 63) wsum[wid] = incl;
        cnt[t] = incl - c;   // within-wave exclusive
    }
    __syncthreads();
    if (t < 512) {
        int wb = 0;
        for (int i = 0; i < wid; ++i) wb += wsum[i];
        int excl = cnt[t] + wb;
        if (t < nb) off[t * NBLK + blk] = (unsigned short)excl;
        if (t == 0) off[nb * NBLK + blk] = (unsigned short)cs;
        cur[t] = excl;
    }
    __syncthreads();
    for (int i = t; i < cs; i += 1024) {
        int cc = col[start + i];         // L2-hot re-read (same 32KB window)
        int rr = row[start + i];
        int p = atomicAdd(&cur[cc >> BSH], 1);
        stage[p] = (rr << BSH) | (cc & (BNODES - 1));
    }
    __syncthreads();
    for (int i = t; i < cs; i += 1024) temp[start + i] = stage[i];
}

// Phase 2: one block per 256-node bucket, 1024 threads. Computes its own
// bucket base bb = sum of off row b (no base[] array), builds ptrS/dinv/csr
// (LDS-staged, coalesced writeback), and fused xw1.
__global__ __launch_bounds__(1024) void k_build(
                        const int* __restrict__ temp, const unsigned short* __restrict__ off,
                        int* __restrict__ ptrS, float* __restrict__ dinv,
                        int* __restrict__ csr,
                        const float* __restrict__ x, const float* __restrict__ W1,
                        unsigned int* __restrict__ h0u, int NBLK, int N, int nb) {
    __shared__ int cnt[BNODES];
    __shared__ int cur[BNODES];
    __shared__ int cellstart[MAXCELL];
    __shared__ int soff[MAXCELL];
    __shared__ int wsum[16];
    __shared__ float sdinv[BNODES];
    __shared__ int s_bb, s_total;
    __shared__ int raw[RAWCAP];
    __shared__ int stage[RAWCAP];
    int b = blockIdx.x;
    int t = threadIdx.x;     // 1024 threads = 16 waves
    int wid = t >> 6, lane = t & 63;
    if (t < BNODES) cnt[t] = 0;
    // phase 0: cell lengths + exclusive scan; also capture s0v for bb reduction
    int len0 = 0, s0v = 0;
    if (t < MAXCELL) {
        if (t < NBLK) {
            s0v = (int)off[b * NBLK + t];
            len0 = (int)off[(b + 1) * NBLK + t] - s0v;
        }
        soff[t] = s0v;
        int v = len0;
        for (int o = 1; o < 64; o <<= 1) {
            int u = __shfl_up(v, o, 64);
            if (lane >= o) v += u;
        }
        if (lane == 63) wsum[wid] = v;
        cellstart[t] = v - len0;
    }
    __syncthreads();
    if (t < MAXCELL) {
        int wb = 0;
        for (int i = 0; i < wid; ++i) wb += wsum[i];
        cellstart[t] += wb;
    }
    if (t == NBLK - 1) s_total = cellstart[t] + len0;   // own value, just updated
    __syncthreads();                                    // wsum now reusable
    // bb = sum of off row b (s0v across t<NBLK; 0 elsewhere)
    int sv = s0v;
    for (int o = 32; o > 0; o >>= 1) sv += __shfl_down(sv, o, 64);
    if (lane == 0 && wid < 8) wsum[wid] = sv;
    __syncthreads();
    if (t == 0) {
        int bbl = 0;
        for (int i = 0; i < 8; ++i) bbl += wsum[i];
        s_bb = bbl;
    }
    __syncthreads();
    int bb = s_bb;
    int total = s_total;
    if (b == nb - 1 && t == 0) ptrS[N] = bb + total;    // = E
    // Phase A: 16-lane-group per cell, coalesced load into raw[], histogram fused
    int grp = t >> 4, gl = t & 15;     // 64 groups of 16 lanes
    for (int cell = grp; cell < NBLK; cell += 64) {
        int s0 = soff[cell];
        int rb = cellstart[cell];
        int len = ((cell + 1 < NBLK) ? cellstart[cell + 1] : total) - rb;
        const int* src = temp + cell * CHUNK + s0;
        for (int j = gl; j < len; j += 16) {
            int e = src[j];
            atomicAdd(&cnt[e & (BNODES - 1)], 1);
            int idx = rb + j;
            if (idx < RAWCAP) raw[idx] = e;
        }
    }
    __syncthreads();
    int c = 0, sincl = 0;
    if (t < BNODES) {
        c = cnt[t];
        sincl = c;
        for (int o = 1; o < 64; o <<= 1) {
            int u = __shfl_up(sincl, o, 64);
            if (lane >= o) sincl += u;
        }
        if (lane == 63) wsum[wid] = sincl;
    }
    __syncthreads();
    if (t < BNODES) {
        int wb2 = 0;
        for (int i = 0; i < wid; ++i) wb2 += wsum[i];
        int lstart = sincl - c + wb2;
        int node = (b << BSH) + t;
        float dv = rsqrtf(1.0f + (float)c);
        sdinv[t] = dv;
        if (node < N) {
            ptrS[node] = bb + lstart;
            dinv[node] = dv;
        }
        cur[t] = lstart;
    }
    __syncthreads();
    int cap = total > RAWCAP ? RAWCAP : total;
    for (int i = t; i < cap; i += 1024) {
        int e = raw[i];
        int p = atomicAdd(&cur[e & (BNODES - 1)], 1);
        int r = e >> BSH;
        if (p < RAWCAP) stage[p] = r;
        else            csr[bb + p] = r;   // statistically unreachable
    }
    if (total > RAWCAP) {                  // statistically unreachable spill
        for (int cell = grp; cell < NBLK; cell += 64) {
            int s0 = soff[cell];
            int rb = cellstart[cell];
            int len = ((cell + 1 < NBLK) ? cellstart[cell + 1] : total) - rb;
            const int* src = temp + cell * CHUNK + s0;
            for (int j = gl; j < len; j += 16) {
                if (rb + j >= RAWCAP) {
                    int e = src[j];
                    int p = atomicAdd(&cur[e & (BNODES - 1)], 1);
                    int r = e >> BSH;
                    if (p < RAWCAP) stage[p] = r;
                    else            csr[bb + p] = r;
                }
            }
        }
    }
    __syncthreads();
    for (int i = t; i < cap; i += 1024) csr[bb + i] = stage[i];
    // Fused xw1 epilogue for this bucket's 256 nodes (2048 packed u32 writes).
    for (int i = t; i < BNODES * 8; i += 1024) {
        int vl = i >> 3, k2 = i & 7, k = k2 * 2;
        int v = (b << BSH) + vl;
        if (v < N) {
            float x0 = x[v * 3 + 0], x1 = x[v * 3 + 1], x2 = x[v * 3 + 2];
            float d = sdinv[vl];
            H2 p;
            p.h[0] = (_Float16)(d * (x0 * W1[k]     + x1 * W1[16 + k]     + x2 * W1[32 + k]));
            p.h[1] = (_Float16)(d * (x0 * W1[k + 1] + x1 * W1[16 + k + 1] + x2 * W1[32 + k + 1]));
            h0u[v * 8 + k2] = p.u;
        }
    }
}

// Layer-1 gather: 8 lanes/node, packed-u32 rows (unchanged).
__global__ void k_gather1(const int* __restrict__ ptrS, const int* __restrict__ csr,
                          const float* __restrict__ dinv, const unsigned int* __restrict__ h0u,
                          const float* __restrict__ W2, const float* __restrict__ b1,
                          unsigned int* __restrict__ h1u, int N) {
    __shared__ float sW[256];
    sW[threadIdx.x] = W2[threadIdx.x];
    __syncthreads();
    int t = blockIdx.x * blockDim.x + threadIdx.x;
    int v = t >> 3, gl = t & 7, k = gl * 2;
    if (v >= N) return;
    int s = ptrS[v], e = ptrS[v + 1];
    float al0 = 0.0f, ah0 = 0.0f, al1 = 0.0f, ah1 = 0.0f;
    int i = s;
    for (; i + 7 < e; i += 8) {
        int myr = __builtin_nontemporal_load(csr + i + gl);
#pragma unroll
        for (int q = 0; q < 8; ++q) {
            int r = __shfl(myr, q, 8);
            H2 p; p.u = h0u[r * 8 + gl];
            if (q & 1) { al1 += (float)p.h[0]; ah1 += (float)p.h[1]; }
            else       { al0 += (float)p.h[0]; ah0 += (float)p.h[1]; }
        }
    }
    if (i < e) {
        int rem = e - i;
        int myr = (gl < rem) ? __builtin_nontemporal_load(csr + i + gl) : 0;
        for (int q = 0; q < rem; ++q) {
            int r = __shfl(myr, q, 8);
            H2 p; p.u = h0u[r * 8 + gl];
            al0 += (float)p.h[0]; ah0 += (float)p.h[1];
        }
    }
    H2 selfp; selfp.u = h0u[v * 8 + gl];
    float d = dinv[v];
    float h_lo = fmaxf(d * (al0 + al1 + (float)selfp.h[0]) + b1[k], 0.0f);
    float h_hi = fmaxf(d * (ah0 + ah1 + (float)selfp.h[1]) + b1[k + 1], 0.0f);
    float o0 = 0.0f, o1 = 0.0f;
#pragma unroll
    for (int j = 0; j < 8; ++j) {
        float hl = __shfl(h_lo, j, 8);
        float hh = __shfl(h_hi, j, 8);
        o0 += hl * sW[(2 * j) * 16 + k]     + hh * sW[(2 * j + 1) * 16 + k];
        o1 += hl * sW[(2 * j) * 16 + k + 1] + hh * sW[(2 * j + 1) * 16 + k + 1];
    }
    H2 outp;
    outp.h[0] = (_Float16)(d * o0);
    outp.h[1] = (_Float16)(d * o1);
    __builtin_nontemporal_store(outp.u, h1u + v * 8 + gl);
}

// Layer-2 gather + bias + pool with wave pre-reduction (no fence, no ticket).
__global__ void k_gather2(const int* __restrict__ ptrS, const int* __restrict__ csr,
                          const float* __restrict__ dinv, const unsigned int* __restrict__ h1u,
                          const float* __restrict__ b2, const int* __restrict__ batch,
                          float* __restrict__ g, int N) {
    int t = blockIdx.x * blockDim.x + threadIdx.x;
    int v = t >> 3, gl = t & 7, k = gl * 2;
    bool valid = (v < N);
    float val0 = 0.0f, val1 = 0.0f;
    int bg = 0;
    if (valid) {
        int s = ptrS[v], e = ptrS[v + 1];
        float al0 = 0.0f, ah0 = 0.0f, al1 = 0.0f, ah1 = 0.0f;
        int i = s;
        for (; i + 7 < e; i += 8) {
            int myr = __builtin_nontemporal_load(csr + i + gl);
#pragma unroll
            for (int q = 0; q < 8; ++q) {
                int r = __shfl(myr, q, 8);
                H2 p; p.u = h1u[r * 8 + gl];
                if (q & 1) { al1 += (float)p.h[0]; ah1 += (float)p.h[1]; }
                else       { al0 += (float)p.h[0]; ah0 += (float)p.h[1]; }
            }
        }
        if (i < e) {
            int rem = e - i;
            int myr = (gl < rem) ? __builtin_nontemporal_load(csr + i + gl) : 0;
            for (int q = 0; q < rem; ++q) {
                int r = __shfl(myr, q, 8);
                H2 p; p.u = h1u[r * 8 + gl];
                al0 += (float)p.h[0]; ah0 += (float)p.h[1];
            }
        }
        H2 selfp; selfp.u = h1u[v * 8 + gl];
        float d = dinv[v];
        val0 = d * (al0 + al1 + (float)selfp.h[0]) + b2[k];
        val1 = d * (ah0 + ah1 + (float)selfp.h[1]) + b2[k + 1];
        bg = batch[v];
    }
    int lane = threadIdx.x & 63;
    int bg0 = __shfl(bg, lane & 7, 64);
    bool uni = __all(valid && (bg == bg0));
    if (uni) {
        val0 += __shfl_xor(val0, 8, 64);
        val0 += __shfl_xor(val0, 16, 64);
        val0 += __shfl_xor(val0, 32, 64);
        val1 += __shfl_xor(val1, 8, 64);
        val1 += __shfl_xor(val1, 16, 64);
        val1 += __shfl_xor(val1, 32, 64);
        if (lane < 8) {
            atomicAdd(&g[bg * 16 + k], val0);
            atomicAdd(&g[bg * 16 + k + 1], val1);
        }
    } else if (valid) {
        atomicAdd(&g[bg * 16 + k], val0);
        atomicAdd(&g[bg * 16 + k + 1], val1);
    }
}

// logits = g @ Wl + bl (16x7), then log_softmax over 7. One thread per graph.
__global__ void k_head(const float* __restrict__ g, const float* __restrict__ Wl,
                       const float* __restrict__ bl, float* __restrict__ out, int G) {
    int gi = blockIdx.x * blockDim.x + threadIdx.x;
    if (gi >= G) return;
    float gv[16];
#pragma unroll
    for (int k = 0; k < 16; ++k) gv[k] = g[gi * 16 + k];
    float lo[7];
    float mx = -1e30f;
#pragma unroll
    for (int j = 0; j < 7; ++j) {
        float a = bl[j];
#pragma unroll
        for (int k = 0; k < 16; ++k) a += gv[k] * Wl[k * 7 + j];
        lo[j] = a;
        mx = fmaxf(mx, a);
    }
    float s = 0.0f;
#pragma unroll
    for (int j = 0; j < 7; ++j) s += expf(lo[j] - mx);
    float lse = mx + logf(s);
#pragma unroll
    for (int j = 0; j < 7; ++j) out[gi * 7 + j] = lo[j] - lse;
}

extern "C" void kernel_launch(void* const* d_in, const int* in_sizes, int n_in,
                              void* d_out, int out_size, void* d_ws, size_t ws_size,
                              hipStream_t stream) {
    const float* x    = (const float*)d_in[0];
    const int*   ei   = (const int*)d_in[1];   // [2, E]: row = ei[0:E), col = ei[E:2E)
    const int*   batch = (const int*)d_in[3];
    const float* W1 = (const float*)d_in[4];
    const float* b1 = (const float*)d_in[5];
    const float* W2 = (const float*)d_in[6];
    const float* b2 = (const float*)d_in[7];
    const float* Wl = (const float*)d_in[8];
    const float* bl = (const float*)d_in[9];
    float* out = (float*)d_out;

    const int N = in_sizes[0] / 3;
    const int E = in_sizes[1] / 2;
    const int G = out_size / 7;

    const int* row = ei;
    const int* col = ei + E;

    const int NBLK = (E + CHUNK - 1) / CHUNK;   // must be <= MAXCELL
    const int nb   = (N + BNODES - 1) >> BSH;   // must be <= 511

    int* w = (int*)d_ws;
    float* dinv = (float*)w;            w += N;
    int*   ptrS = w;                    w += N + 1;
    unsigned short* off = (unsigned short*)w;
    w += ((nb + 1) * NBLK + 1) / 2;     // ushort table, rounded up to int units
    int*   csr  = w;                    w += E;
    int*   temp = w;                    w += E;
    unsigned int* h0u = (unsigned int*)w;  w += 8 * N;
    unsigned int* h1u = (unsigned int*)w;  w += 8 * N;
    float* g    = (float*)w;            w += 16 * G;

    const int TB = 256;
    const int n8  = N * 8;
    const int G16 = G * 16;

    k_bin<<<NBLK, 1024, 0, stream>>>(row, col, temp, off, g, E, NBLK, nb, G16);
    k_build<<<nb, 1024, 0, stream>>>(temp, off, ptrS, dinv, csr, x, W1, h0u, NBLK, N, nb);
    k_gather1<<<(n8 + TB - 1) / TB, TB, 0, stream>>>(ptrS, csr, dinv, h0u, W2, b1, h1u, N);
    k_gather2<<<(n8 + TB - 1) / TB, TB, 0, stream>>>(ptrS, csr, dinv, h1u, b2, batch, g, N);
    k_head<<<(G + TB - 1) / TB, TB, 0, stream>>>(g, Wl, bl, out, G);
}

// Round 15
// 187.675 us; speedup vs baseline: 4.2020x; 1.0073x over previous
//
#include <hip/hip_runtime.h>
#include <math.h>

#define CHUNK 8192
#define BSH 8            // bucket shift: 256 nodes per bucket
#define BNODES 256
#define RAWCAP 9216      // LDS edge capacity per bucket (avg 8192, sigma ~90)
#define MAXCELL 512      // max chunks supported (E <= 4.19M); also requires nb <= 511

// Workspace layout (4-byte units, NO aliasing; ~33 MB total):
//   dinv  : N            rsqrt(1+deg)
//   ptrS  : N+1          CSR row starts (ptrS[N] = E)
//   off   : (nb+1)*NBLK  ushort per-(bucket,chunk) exclusive offsets
//   csr   : E            source nodes grouped by destination
//   temp  : E            binned packed edges
//   h0u   : 8N u32       packed fp16 feature table, layer-1 input (dinv-premultiplied)
//   h1u   : 8N u32       packed fp16 feature table, layer-2 input
//   g     : 16G          pooled graph accumulator

union H2 { unsigned int u; _Float16 h[2]; };

// Phase 1: bin this block's 8192-edge chunk by destination bucket.
// Also zeroes g (grid-stride).
__global__ __launch_bounds__(1024) void k_bin(
                      const int* __restrict__ row, const int* __restrict__ col,
                      int* __restrict__ temp, unsigned short* __restrict__ off,
                      float* __restrict__ g,
                      int E, int NBLK, int nb, int G16) {
    __shared__ int cnt[512];
    __shared__ int cur[512];
    __shared__ int wsum[16];
    __shared__ int stage[CHUNK];
    int blk = blockIdx.x;
    int start = blk * CHUNK;
    int cs = E - start; if (cs > CHUNK) cs = CHUNK;
    int t = threadIdx.x;     // 1024 threads = 16 waves
    int wid = t >> 6, lane = t & 63;
    for (int i = blk * 1024 + t; i < G16; i += gridDim.x * 1024) g[i] = 0.0f;
    if (t < 512) cnt[t] = 0;
    __syncthreads();
    for (int i = t; i < cs; i += 1024) atomicAdd(&cnt[col[start + i] >> BSH], 1);
    __syncthreads();
    if (t < 512) {           // waves 0..7 scan the 512 bucket counters
        int c = cnt[t];
        int incl = c;
        for (int o = 1; o < 64; o <<= 1) {
            int u = __shfl_up(incl, o, 64);
            if (lane >= o) incl += u;
        }
        if (lane == 63) wsum[wid] = incl;
        cnt[t] = incl - c;   // within-wave exclusive
    }
    __syncthreads();
    if (t < 512) {
        int wb = 0;
        for (int i = 0; i < wid; ++i) wb += wsum[i];
        int excl = cnt[t] + wb;
        if (t < nb) off[t * NBLK + blk] = (unsigned short)excl;
        if (t == 0) off[nb * NBLK + blk] = (unsigned short)cs;
        cur[t] = excl;
    }
    __syncthreads();
    for (int i = t; i < cs; i += 1024) {
        int cc = col[start + i];         // L2-hot re-read (same 32KB window)
        int rr = row[start + i];
        int p = atomicAdd(&cur[cc >> BSH], 1);
        stage[p] = (rr << BSH) | (cc & (BNODES - 1));
    }
    __syncthreads();
    for (int i = t; i < cs; i += 1024) temp[start + i] = stage[i];
}

// Phase 2: one block per 256-node bucket, 1024 threads. Computes its own
// bucket base bb = sum of off row b (no base[] array), builds ptrS/dinv/csr
// (LDS-staged, coalesced writeback), and fused xw1.
__global__ __launch_bounds__(1024) void k_build(
                        const int* __restrict__ temp, const unsigned short* __restrict__ off,
                        int* __restrict__ ptrS, float* __restrict__ dinv,
                        int* __restrict__ csr,
                        const float* __restrict__ x, const float* __restrict__ W1,
                        unsigned int* __restrict__ h0u, int NBLK, int N, int nb) {
    __shared__ int cnt[BNODES];
    __shared__ int cur[BNODES];
    __shared__ int cellstart[MAXCELL];
    __shared__ int soff[MAXCELL];
    __shared__ int wsum[16];
    __shared__ float sdinv[BNODES];
    __shared__ int s_bb, s_total;
    __shared__ int raw[RAWCAP];
    __shared__ int stage[RAWCAP];
    int b = blockIdx.x;
    int t = threadIdx.x;     // 1024 threads = 16 waves
    int wid = t >> 6, lane = t & 63;
    if (t < BNODES) cnt[t] = 0;
    // phase 0: cell lengths + exclusive scan; also capture s0v for bb reduction
    int len0 = 0, s0v = 0;
    if (t < MAXCELL) {
        if (t < NBLK) {
            s0v = (int)off[b * NBLK + t];
            len0 = (int)off[(b + 1) * NBLK + t] - s0v;
        }
        soff[t] = s0v;
        int v = len0;
        for (int o = 1; o < 64; o <<= 1) {
            int u = __shfl_up(v, o, 64);
            if (lane >= o) v += u;
        }
        if (lane == 63) wsum[wid] = v;
        cellstart[t] = v - len0;
    }
    __syncthreads();
    if (t < MAXCELL) {
        int wb = 0;
        for (int i = 0; i < wid; ++i) wb += wsum[i];
        cellstart[t] += wb;
    }
    if (t == NBLK - 1) s_total = cellstart[t] + len0;   // own value, just updated
    __syncthreads();                                    // wsum now reusable
    // bb = sum of off row b (s0v across t<NBLK; 0 elsewhere)
    int sv = s0v;
    for (int o = 32; o > 0; o >>= 1) sv += __shfl_down(sv, o, 64);
    if (lane == 0 && wid < 8) wsum[wid] = sv;
    __syncthreads();
    if (t == 0) {
        int bbl = 0;
        for (int i = 0; i < 8; ++i) bbl += wsum[i];
        s_bb = bbl;
    }
    __syncthreads();
    int bb = s_bb;
    int total = s_total;
    if (b == nb - 1 && t == 0) ptrS[N] = bb + total;    // = E
    // Phase A: 16-lane-group per cell, coalesced load into raw[], histogram fused
    int grp = t >> 4, gl = t & 15;     // 64 groups of 16 lanes
    for (int cell = grp; cell < NBLK; cell += 64) {
        int s0 = soff[cell];
        int rb = cellstart[cell];
        int len = ((cell + 1 < NBLK) ? cellstart[cell + 1] : total) - rb;
        const int* src = temp + cell * CHUNK + s0;
        for (int j = gl; j < len; j += 16) {
            int e = src[j];
            atomicAdd(&cnt[e & (BNODES - 1)], 1);
            int idx = rb + j;
            if (idx < RAWCAP) raw[idx] = e;
        }
    }
    __syncthreads();
    int c = 0, sincl = 0;
    if (t < BNODES) {
        c = cnt[t];
        sincl = c;
        for (int o = 1; o < 64; o <<= 1) {
            int u = __shfl_up(sincl, o, 64);
            if (lane >= o) sincl += u;
        }
        if (lane == 63) wsum[wid] = sincl;
    }
    __syncthreads();
    if (t < BNODES) {
        int wb2 = 0;
        for (int i = 0; i < wid; ++i) wb2 += wsum[i];
        int lstart = sincl - c + wb2;
        int node = (b << BSH) + t;
        float dv = rsqrtf(1.0f + (float)c);
        sdinv[t] = dv;
        if (node < N) {
            ptrS[node] = bb + lstart;
            dinv[node] = dv;
        }
        cur[t] = lstart;
    }
    __syncthreads();
    int cap = total > RAWCAP ? RAWCAP : total;
    for (int i = t; i < cap; i += 1024) {
        int e = raw[i];
        int p = atomicAdd(&cur[e & (BNODES - 1)], 1);
        int r = e >> BSH;
        if (p < RAWCAP) stage[p] = r;
        else            csr[bb + p] = r;   // statistically unreachable
    }
    if (total > RAWCAP) {                  // statistically unreachable spill
        for (int cell = grp; cell < NBLK; cell += 64) {
            int s0 = soff[cell];
            int rb = cellstart[cell];
            int len = ((cell + 1 < NBLK) ? cellstart[cell + 1] : total) - rb;
            const int* src = temp + cell * CHUNK + s0;
            for (int j = gl; j < len; j += 16) {
                if (rb + j >= RAWCAP) {
                    int e = src[j];
                    int p = atomicAdd(&cur[e & (BNODES - 1)], 1);
                    int r = e >> BSH;
                    if (p < RAWCAP) stage[p] = r;
                    else            csr[bb + p] = r;
                }
            }
        }
    }
    __syncthreads();
    for (int i = t; i < cap; i += 1024) csr[bb + i] = stage[i];
    // Fused xw1 epilogue for this bucket's 256 nodes (2048 packed u32 writes).
    for (int i = t; i < BNODES * 8; i += 1024) {
        int vl = i >> 3, k2 = i & 7, k = k2 * 2;
        int v = (b << BSH) + vl;
        if (v < N) {
            float x0 = x[v * 3 + 0], x1 = x[v * 3 + 1], x2 = x[v * 3 + 2];
            float d = sdinv[vl];
            H2 p;
            p.h[0] = (_Float16)(d * (x0 * W1[k]     + x1 * W1[16 + k]     + x2 * W1[32 + k]));
            p.h[1] = (_Float16)(d * (x0 * W1[k + 1] + x1 * W1[16 + k + 1] + x2 * W1[32 + k + 1]));
            h0u[v * 8 + k2] = p.u;
        }
    }
}

// Layer-1 gather: 8 lanes/node, packed-u32 rows, software-pipelined csr
// prefetch (next window's index load issued under current window's table loads).
__global__ void k_gather1(const int* __restrict__ ptrS, const int* __restrict__ csr,
                          const float* __restrict__ dinv, const unsigned int* __restrict__ h0u,
                          const float* __restrict__ W2, const float* __restrict__ b1,
                          unsigned int* __restrict__ h1u, int N) {
    __shared__ float sW[256];
    sW[threadIdx.x] = W2[threadIdx.x];
    __syncthreads();
    int t = blockIdx.x * blockDim.x + threadIdx.x;
    int v = t >> 3, gl = t & 7, k = gl * 2;
    if (v >= N) return;
    int s = ptrS[v], e = ptrS[v + 1];
    // hoisted independent loads (issue early, consumed late)
    H2 selfp; selfp.u = h0u[v * 8 + gl];
    float d = dinv[v];
    float bk0 = b1[k], bk1 = b1[k + 1];
    float al0 = 0.0f, ah0 = 0.0f, al1 = 0.0f, ah1 = 0.0f;
    int i = s;
    int myr = (i + 7 < e) ? __builtin_nontemporal_load(csr + i + gl) : 0;
    for (; i + 7 < e; ) {
        int inext = i + 8;
        int nxt = (inext + 7 < e) ? __builtin_nontemporal_load(csr + inext + gl) : 0;
#pragma unroll
        for (int q = 0; q < 8; ++q) {
            int r = __shfl(myr, q, 8);
            H2 p; p.u = h0u[r * 8 + gl];
            if (q & 1) { al1 += (float)p.h[0]; ah1 += (float)p.h[1]; }
            else       { al0 += (float)p.h[0]; ah0 += (float)p.h[1]; }
        }
        myr = nxt;
        i = inext;
    }
    if (i < e) {
        int rem = e - i;
        int tr = (gl < rem) ? __builtin_nontemporal_load(csr + i + gl) : 0;
        for (int q = 0; q < rem; ++q) {
            int r = __shfl(tr, q, 8);
            H2 p; p.u = h0u[r * 8 + gl];
            al0 += (float)p.h[0]; ah0 += (float)p.h[1];
        }
    }
    float h_lo = fmaxf(d * (al0 + al1 + (float)selfp.h[0]) + bk0, 0.0f);
    float h_hi = fmaxf(d * (ah0 + ah1 + (float)selfp.h[1]) + bk1, 0.0f);
    float o0 = 0.0f, o1 = 0.0f;
#pragma unroll
    for (int j = 0; j < 8; ++j) {
        float hl = __shfl(h_lo, j, 8);
        float hh = __shfl(h_hi, j, 8);
        o0 += hl * sW[(2 * j) * 16 + k]     + hh * sW[(2 * j + 1) * 16 + k];
        o1 += hl * sW[(2 * j) * 16 + k + 1] + hh * sW[(2 * j + 1) * 16 + k + 1];
    }
    H2 outp;
    outp.h[0] = (_Float16)(d * o0);
    outp.h[1] = (_Float16)(d * o1);
    __builtin_nontemporal_store(outp.u, h1u + v * 8 + gl);
}

// Layer-2 gather + bias + pool with wave pre-reduction (prefetch-pipelined).
__global__ void k_gather2(const int* __restrict__ ptrS, const int* __restrict__ csr,
                          const float* __restrict__ dinv, const unsigned int* __restrict__ h1u,
                          const float* __restrict__ b2, const int* __restrict__ batch,
                          float* __restrict__ g, int N) {
    int t = blockIdx.x * blockDim.x + threadIdx.x;
    int v = t >> 3, gl = t & 7, k = gl * 2;
    bool valid = (v < N);
    float val0 = 0.0f, val1 = 0.0f;
    int bg = 0;
    if (valid) {
        int s = ptrS[v], e = ptrS[v + 1];
        H2 selfp; selfp.u = h1u[v * 8 + gl];
        float d = dinv[v];
        float bk0 = b2[k], bk1 = b2[k + 1];
        bg = batch[v];
        float al0 = 0.0f, ah0 = 0.0f, al1 = 0.0f, ah1 = 0.0f;
        int i = s;
        int myr = (i + 7 < e) ? __builtin_nontemporal_load(csr + i + gl) : 0;
        for (; i + 7 < e; ) {
            int inext = i + 8;
            int nxt = (inext + 7 < e) ? __builtin_nontemporal_load(csr + inext + gl) : 0;
#pragma unroll
            for (int q = 0; q < 8; ++q) {
                int r = __shfl(myr, q, 8);
                H2 p; p.u = h1u[r * 8 + gl];
                if (q & 1) { al1 += (float)p.h[0]; ah1 += (float)p.h[1]; }
                else       { al0 += (float)p.h[0]; ah0 += (float)p.h[1]; }
            }
            myr = nxt;
            i = inext;
        }
        if (i < e) {
            int rem = e - i;
            int tr = (gl < rem) ? __builtin_nontemporal_load(csr + i + gl) : 0;
            for (int q = 0; q < rem; ++q) {
                int r = __shfl(tr, q, 8);
                H2 p; p.u = h1u[r * 8 + gl];
                al0 += (float)p.h[0]; ah0 += (float)p.h[1];
            }
        }
        val0 = d * (al0 + al1 + (float)selfp.h[0]) + bk0;
        val1 = d * (ah0 + ah1 + (float)selfp.h[1]) + bk1;
    }
    int lane = threadIdx.x & 63;
    int bg0 = __shfl(bg, lane & 7, 64);
    bool uni = __all(valid && (bg == bg0));
    if (uni) {
        val0 += __shfl_xor(val0, 8, 64);
        val0 += __shfl_xor(val0, 16, 64);
        val0 += __shfl_xor(val0, 32, 64);
        val1 += __shfl_xor(val1, 8, 64);
        val1 += __shfl_xor(val1, 16, 64);
        val1 += __shfl_xor(val1, 32, 64);
        if (lane < 8) {
            atomicAdd(&g[bg * 16 + k], val0);
            atomicAdd(&g[bg * 16 + k + 1], val1);
        }
    } else if (valid) {
        atomicAdd(&g[bg * 16 + k], val0);
        atomicAdd(&g[bg * 16 + k + 1], val1);
    }
}

// logits = g @ Wl + bl (16x7), then log_softmax over 7. One thread per graph.
__global__ void k_head(const float* __restrict__ g, const float* __restrict__ Wl,
                       const float* __restrict__ bl, float* __restrict__ out, int G) {
    int gi = blockIdx.x * blockDim.x + threadIdx.x;
    if (gi >= G) return;
    float gv[16];
#pragma unroll
    for (int k = 0; k < 16; ++k) gv[k] = g[gi * 16 + k];
    float lo[7];
    float mx = -1e30f;
#pragma unroll
    for (int j = 0; j < 7; ++j) {
        float a = bl[j];
#pragma unroll
        for (int k = 0; k < 16; ++k) a += gv[k] * Wl[k * 7 + j];
        lo[j] = a;
        mx = fmaxf(mx, a);
    }
    float s = 0.0f;
#pragma unroll
    for (int j = 0; j < 7; ++j) s += expf(lo[j] - mx);
    float lse = mx + logf(s);
#pragma unroll
    for (int j = 0; j < 7; ++j) out[gi * 7 + j] = lo[j] - lse;
}

extern "C" void kernel_launch(void* const* d_in, const int* in_sizes, int n_in,
                              void* d_out, int out_size, void* d_ws, size_t ws_size,
                              hipStream_t stream) {
    const float* x    = (const float*)d_in[0];
    const int*   ei   = (const int*)d_in[1];   // [2, E]: row = ei[0:E), col = ei[E:2E)
    const int*   batch = (const int*)d_in[3];
    const float* W1 = (const float*)d_in[4];
    const float* b1 = (const float*)d_in[5];
    const float* W2 = (const float*)d_in[6];
    const float* b2 = (const float*)d_in[7];
    const float* Wl = (const float*)d_in[8];
    const float* bl = (const float*)d_in[9];
    float* out = (float*)d_out;

    const int N = in_sizes[0] / 3;
    const int E = in_sizes[1] / 2;
    const int G = out_size / 7;

    const int* row = ei;
    const int* col = ei + E;

    const int NBLK = (E + CHUNK - 1) / CHUNK;   // must be <= MAXCELL
    const int nb   = (N + BNODES - 1) >> BSH;   // must be <= 511

    int* w = (int*)d_ws;
    float* dinv = (float*)w;            w += N;
    int*   ptrS = w;                    w += N + 1;
    unsigned short* off = (unsigned short*)w;
    w += ((nb + 1) * NBLK + 1) / 2;     // ushort table, rounded up to int units
    int*   csr  = w;                    w += E;
    int*   temp = w;                    w += E;
    unsigned int* h0u = (unsigned int*)w;  w += 8 * N;
    unsigned int* h1u = (unsigned int*)w;  w += 8 * N;
    float* g    = (float*)w;            w += 16 * G;

    const int TB = 256;
    const int n8  = N * 8;
    const int G16 = G * 16;

    k_bin<<<NBLK, 1024, 0, stream>>>(row, col, temp, off, g, E, NBLK, nb, G16);
    k_build<<<nb, 1024, 0, stream>>>(temp, off, ptrS, dinv, csr, x, W1, h0u, NBLK, N, nb);
    k_gather1<<<(n8 + TB - 1) / TB, TB, 0, stream>>>(ptrS, csr, dinv, h0u, W2, b1, h1u, N);
    k_gather2<<<(n8 + TB - 1) / TB, TB, 0, stream>>>(ptrS, csr, dinv, h1u, b2, batch, g, N);
    k_head<<<(G + TB - 1) / TB, TB, 0, stream>>>(g, Wl, bl, out, G);
}